// Round 7
// baseline (34.968 us; speedup 1.0000x reference)
//
#include <hip/hip_runtime.h>
#include <math.h>

// ---------------------------------------------------------------------------
// SpikingColorVision: 4 pops x 8 ch Izhikevich RS neurons, 1000 Euler steps.
// Single 64-lane wave; serial recurrence bound by dep-chain x issue at the
// fixed lone-wave clock (~0.8 GHz; DVFS ramp attempts failed in R3/R5).
//
// R7: restore R4's TRUE 4-hop chain (U' selected by cndmask at the same hop
// as v' -- R5/R6's fma(2000,sv,Un) made it 5 hops), and remove the 2
// rate-ops/step via a spike BITMAP: one fused asm block does
//   v_cmp_ge_f32 vcc, vn, 30 ; cndmask v' ; cndmask U' ; v_addc B=2B+spike
// Rate is rebuilt per 32-step word: R = fma(.95^32, R, W(B)) with W from a
// 256-entry LDS table of byte spike-weights (previous word folded during the
// current block -> LDS latency hidden).
//
// Step (4-hop cycle v->w/d3->vn->cmp->sel; 10 VALU + 1 load + 0.5 fold):
//   I3 = fma(.3, eps, Ib140)      [off-chain]
//   d3 = fma(-.004, U, I3)        [h1]   w  = fma(.04, v, 6)   [h1]
//   Un = fma(.98, U, v) [h1]      U8 = Un + 2000               [h2]
//   vn = fma(w, v, d3)            [h2]
//   asm: cmp[h3]; v'=sel(vn,-65); U'=sel(Un,U8); B=2B+sp  [h4]
// v/U trajectory is BIT-IDENTICAL to R6 (validated absmax 0.0); only the
// rate accumulation is reassociated (word-Horner) -> expected absmax ~1e-7.
// ---------------------------------------------------------------------------

#define FSTEP(eps) do {                                          \
    float I3_ = __builtin_fmaf(0.3f, (eps), Ib140);              \
    float d3_ = __builtin_fmaf(-0.004f, U, I3_);                 \
    float w_  = __builtin_fmaf(0.04f, v, 6.0f);                  \
    float Un_ = __builtin_fmaf(0.98f, U, v);                     \
    float U8_ = Un_ + 2000.0f;                                   \
    float vn_ = __builtin_fmaf(w_, v, d3_);                      \
    float vo_, Uo_;                                              \
    asm("v_cmp_ge_f32 vcc, %3, %5\n\t"                           \
        "v_cndmask_b32 %0, %3, %6, vcc\n\t"                      \
        "v_cndmask_b32 %1, %4, %7, vcc\n\t"                      \
        "v_addc_co_u32 %2, vcc, %2, %2, vcc"                     \
        : "=&v"(vo_), "=&v"(Uo_), "+v"(B)                        \
        : "v"(vn_), "v"(Un_), "v"(c30), "v"(c65), "v"(U8_)       \
        : "vcc");                                                \
    v = vo_; U = Uo_;                                            \
  } while (0)

// Fold one 32-bit spike word (bit i has weight .95^i; bit 31 = oldest step
// of the word) into R:  R = .95^32 * R + W(word).
#define FOLD32(word) do {                                        \
    float t0_ = Tsh[(word) & 255u];                              \
    float t1_ = Tsh[((word) >> 8) & 255u];                       \
    float t2_ = Tsh[((word) >> 16) & 255u];                      \
    float t3_ = Tsh[(word) >> 24];                               \
    float W_  = __builtin_fmaf(C8, t3_, t2_);                    \
    W_ = __builtin_fmaf(C8, W_, t1_);                            \
    W_ = __builtin_fmaf(C8, W_, t0_);                            \
    R  = __builtin_fmaf(C32, R, W_);                             \
  } while (0)

#define LOAD16(Bf, base) do {                                    \
    Bf##0  = (base)[0*32];  Bf##1  = (base)[1*32];               \
    Bf##2  = (base)[2*32];  Bf##3  = (base)[3*32];               \
    Bf##4  = (base)[4*32];  Bf##5  = (base)[5*32];               \
    Bf##6  = (base)[6*32];  Bf##7  = (base)[7*32];               \
    Bf##8  = (base)[8*32];  Bf##9  = (base)[9*32];               \
    Bf##10 = (base)[10*32]; Bf##11 = (base)[11*32];              \
    Bf##12 = (base)[12*32]; Bf##13 = (base)[13*32];              \
    Bf##14 = (base)[14*32]; Bf##15 = (base)[15*32];              \
  } while (0)

#define STEP16(Bf) do {                                          \
    FSTEP(Bf##0);  FSTEP(Bf##1);  FSTEP(Bf##2);  FSTEP(Bf##3);   \
    FSTEP(Bf##4);  FSTEP(Bf##5);  FSTEP(Bf##6);  FSTEP(Bf##7);   \
    FSTEP(Bf##8);  FSTEP(Bf##9);  FSTEP(Bf##10); FSTEP(Bf##11);  \
    FSTEP(Bf##12); FSTEP(Bf##13); FSTEP(Bf##14); FSTEP(Bf##15);  \
  } while (0)

// Single kernel: drives + 1000-step recurrence + rate decode + outputs.
__global__ __launch_bounds__(64) void scv_kernel(
    const float* __restrict__ retL, const float* __restrict__ retR,
    const float* __restrict__ noise, float* __restrict__ out, int S) {
  const int lane = threadIdx.x;
  const int neuron = lane & 31;  // upper 32 lanes duplicate (wave64 uniform)

  // ---- byte spike-weight table: T[b] = sum_i bit_i(b) * .95^i ----
  __shared__ float Tsh[256];
  {
    const float W95[8] = {1.0f, 0.95f, 0.9025f, 0.857375f, 0.81450625f,
                          0.7737809375f, 0.735091890625f, 0.69833729609375f};
    for (int e = lane; e < 256; e += 64) {
      float val = 0.0f;
#pragma unroll
      for (int i = 0; i < 8; ++i)
        val += (e & (1 << i)) ? W95[i] : 0.0f;
      Tsh[e] = val;
    }
  }
  __syncthreads();

  const float C8a = 0.9025f * 0.9025f;        // .95^4
  const float C8  = C8a * C8a;                // .95^8
  const float C16 = C8 * C8;
  const float C32 = C16 * C16;                // .95^32

  // ---- drives (exact integer counts; any reduction order exact) ----
  float Ib140;
  {
#pragma clang fp contract(off)
    float f = 0.0f, e = 0.0f, r = 0.0f, cp = 0.0f;
    for (int i = lane; i < 800; i += 64) {
      float t = (i < 400) ? retL[i] : retR[i - 400];
      f  += (t > 0.7f) ? 1.0f : 0.0f;
      e  += (fabsf(t - 0.5f)  < 0.1f) ? 1.0f : 0.0f;
      r  += (fabsf(t - 0.75f) < 0.1f) ? 1.0f : 0.0f;
      cp += (fabsf(t - 0.25f) < 0.1f) ? 1.0f : 0.0f;
    }
#pragma unroll
    for (int off = 1; off < 64; off <<= 1) {
      f  += __shfl_xor(f,  off);
      e  += __shfl_xor(e,  off);
      r  += __shfl_xor(r,  off);
      cp += __shfl_xor(cp, off);
    }
    float total = f + e + r + cp + 1e-8f;
    int p = (lane >> 3) & 3;
    float dv;
    if (p == 0)      dv = (f * 0.1f + e * 0.05f + cp * 0.8f + r * 0.2f) / total;
    else if (p == 1) dv = (f * 0.2f + e * 0.1f  + cp * 0.5f + r * 0.3f) / total;
    else if (p == 2) dv = (f * 0.8f + e * 0.3f  + cp * 0.3f + r * 0.3f) / total;
    else             dv = (f * 0.4f + e * 0.7f  + cp * 0.2f + r * 0.3f) / total;
    float Ib = dv * 10.0f + (-2.0f);
    Ib140 = Ib + 140.0f;
  }

  // ---- recurrence ----
  float v = -65.0f;
  float U = -3250.0f;   // 250 * u0, u0 = -13 exactly
  float R = 0.0f;       // decoded spike-weight sum; rate = 0.05 * R
  unsigned int B = 0u;  // current spike word (B = 2B + spike each step)
  unsigned int Bp = 0u; // previous full word (folded one iteration late)
  const float c30 = 30.0f, c65 = -65.0f;

  const float* p = noise + neuron;
  float c0,c1,c2,c3,c4,c5,c6,c7,c8,c9,c10,c11,c12,c13,c14,c15;
  float n0,n1,n2,n3,n4,n5,n6,n7,n8,n9,n10,n11,n12,n13,n14,n15;

  int t = 0;
  int bits = 0;          // valid bits currently in B
  if (S >= 48) {
    LOAD16(c, p); p += 16 * 32;            // steps 0..15 in flight
    for (; t + 48 <= S; t += 32) {
      LOAD16(n, p); p += 16 * 32;          // steps t+16..t+31
      FOLD32(Bp);                          // fold word from previous iter
      STEP16(c);                           // steps t..t+15
      LOAD16(c, p); p += 16 * 32;          // steps t+32..t+47
      STEP16(n);                           // steps t+16..t+31
      Bp = B; B = 0u;                      // word [t, t+32) complete
    }
    FOLD32(Bp); Bp = 0u;                   // fold last full word
    STEP16(c);                             // steps t..t+15
    t += 16;
    bits = 16;
  }
  // tail: scalar loop, fold whenever the word fills
  {
    const float* q = noise + neuron;
    float cur = (t < S) ? q[(size_t)t * 32] : 0.0f;
    for (; t < S; ++t) {
      float nxt = (t + 1 < S) ? q[(size_t)(t + 1) * 32] : 0.0f;
      FSTEP(cur);
      cur = nxt;
      if (++bits == 32) { FOLD32(B); B = 0u; bits = 0; }
    }
  }
  // final partial word: R = .95^bits * R + W(B)
  {
    float t0_ = Tsh[B & 255u];
    float t1_ = Tsh[(B >> 8) & 255u];
    float t2_ = Tsh[(B >> 16) & 255u];
    float t3_ = Tsh[B >> 24];
    float W_  = __builtin_fmaf(C8, t3_, t2_);
    W_ = __builtin_fmaf(C8, W_, t1_);
    W_ = __builtin_fmaf(C8, W_, t0_);
    float pscale = 1.0f;
    for (int i = 0; i < bits; ++i) pscale *= 0.95f;
    R = __builtin_fmaf(pscale, R, W_);
  }

  // ---- outputs ----
  {
#pragma clang fp contract(off)
    float rate = 0.05f * R;
    float rsum = rate;
    rsum += __shfl_xor(rsum, 1);
    rsum += __shfl_xor(rsum, 2);
    rsum += __shfl_xor(rsum, 4);
    float mean = rsum / 8.0f;            // exact /8
    float m_uv = __shfl(mean, 0);
    float m_bl = __shfl(mean, 8);
    float m_gr = __shfl(mean, 16);
    float m_rd = __shfl(mean, 24);
    if (lane == 0) {
      out[0] = m_uv;
      out[1] = m_bl;
      out[2] = m_gr;
      out[3] = m_rd;
      out[4] = m_rd - m_gr;
      out[5] = (m_uv + m_bl) / 2.0f - (m_gr + m_rd) / 2.0f;
    }
  }
}

extern "C" void kernel_launch(void* const* d_in, const int* in_sizes, int n_in,
                              void* d_out, int out_size, void* d_ws,
                              size_t ws_size, hipStream_t stream) {
  const float* retL  = (const float*)d_in[0];
  const float* retR  = (const float*)d_in[1];
  const float* noise = (const float*)d_in[2];
  float* out = (float*)d_out;
  (void)n_in; (void)out_size; (void)d_ws; (void)ws_size;

  const int S = in_sizes[2] / 32;  // substeps
  hipLaunchKernelGGL(scv_kernel, dim3(1), dim3(64), 0, stream, retL, retR,
                     noise, out, S);
}

// Round 8
// 31.940 us; speedup vs baseline: 1.0948x; 1.0948x over previous
//
#include <hip/hip_runtime.h>
#include <math.h>

// ---------------------------------------------------------------------------
// SpikingColorVision: 4 pops x 8 ch Izhikevich RS neurons, 1000 Euler steps.
// Single 64-lane wave. REGIME (established R6/R7): ISSUE-bound at ~2.7ns per
// wave64 VALU instruction (2cy @ ~740MHz effective lone-wave clock; DVFS does
// not ramp inside graph replays -- R3/R5 burners both failed). Chain length
// no longer binds (4- vs 5-hop indistinguishable; issue 22cy > chain 20cy).
//
// Minimal step = 11 instructions (proven minimal by construction attempts:
// speculation, packing, unselected-state all add ops elsewhere):
//   load eps                                   [1]
//   I3 = fma(.3, eps, Ib140)                   [1]  off-chain
//   d3 = fma(-.004, U, I3)                     [1]
//   w  = fma(.04, v, 6)                        [1]
//   Un = fma(.98, U, v)                        [1]
//   vn = fma(w, v, d3)                         [1]
//   cmp vn >= 30                               [1]
//   sv = sel(0,1); v' = sel(vn,-65)            [2]
//   U' = fma(2000, sv, Un); R' = fma(.95,R,sv) [2]
// R8 = R6 loop (the issue-minimal variant, 29.6ns/step measured) + first
// noise loads issued BEFORE the drives block (hides L2 latency under ~250cy
// of drives compute) + float4 drive loads (13 scalar -> 4 vector).
// ---------------------------------------------------------------------------

#define FSTEP(eps) do {                                  \
    float I3_ = __builtin_fmaf(0.3f, (eps), Ib140);      \
    float d3_ = __builtin_fmaf(-0.004f, U, I3_);         \
    float w_  = __builtin_fmaf(0.04f, v, 6.0f);          \
    float Un_ = __builtin_fmaf(0.98f, U, v);             \
    float vn_ = __builtin_fmaf(w_, v, d3_);              \
    bool  sp_ = (vn_ >= 30.0f);                          \
    float sv_ = sp_ ? 1.0f : 0.0f;                       \
    v = sp_ ? -65.0f : vn_;                              \
    U = __builtin_fmaf(2000.0f, sv_, Un_);               \
    R = __builtin_fmaf(0.95f, R, sv_);                   \
  } while (0)

// 16 loads, stride 32 floats (128B) -> immediate offsets, one base register.
#define LOAD16(B, base) do {                             \
    B##0  = (base)[0*32];  B##1  = (base)[1*32];         \
    B##2  = (base)[2*32];  B##3  = (base)[3*32];         \
    B##4  = (base)[4*32];  B##5  = (base)[5*32];         \
    B##6  = (base)[6*32];  B##7  = (base)[7*32];         \
    B##8  = (base)[8*32];  B##9  = (base)[9*32];         \
    B##10 = (base)[10*32]; B##11 = (base)[11*32];        \
    B##12 = (base)[12*32]; B##13 = (base)[13*32];        \
    B##14 = (base)[14*32]; B##15 = (base)[15*32];        \
  } while (0)

#define STEP16(B) do {                                   \
    FSTEP(B##0);  FSTEP(B##1);  FSTEP(B##2);  FSTEP(B##3);   \
    FSTEP(B##4);  FSTEP(B##5);  FSTEP(B##6);  FSTEP(B##7);   \
    FSTEP(B##8);  FSTEP(B##9);  FSTEP(B##10); FSTEP(B##11);  \
    FSTEP(B##12); FSTEP(B##13); FSTEP(B##14); FSTEP(B##15);  \
  } while (0)

#define CLS(tv) do {                                     \
    f  += ((tv) > 0.7f) ? 1.0f : 0.0f;                   \
    e  += (fabsf((tv) - 0.5f)  < 0.1f) ? 1.0f : 0.0f;    \
    r  += (fabsf((tv) - 0.75f) < 0.1f) ? 1.0f : 0.0f;    \
    cp += (fabsf((tv) - 0.25f) < 0.1f) ? 1.0f : 0.0f;    \
  } while (0)

// Single kernel: drives + 1000-step recurrence + outputs, one 64-lane wave.
__global__ __launch_bounds__(64) void scv_kernel(
    const float* __restrict__ retL, const float* __restrict__ retR,
    const float* __restrict__ noise, float* __restrict__ out, int S) {
  const int lane = threadIdx.x;
  const int neuron = lane & 31;  // upper 32 lanes duplicate (wave64 uniform)

  // ---- issue the first noise block's loads NOW (latency hides under the
  //      drives computation below) ----
  const float* p = noise + neuron;
  float c0,c1,c2,c3,c4,c5,c6,c7,c8,c9,c10,c11,c12,c13,c14,c15;
  float n0,n1,n2,n3,n4,n5,n6,n7,n8,n9,n10,n11,n12,n13,n14,n15;
  const bool main_path = (S >= 48);
  if (main_path) { LOAD16(c, p); p += 16 * 32; }

  // ---- drives (exact integer counts; any reduction order exact) ----
  float Ib140;
  {
#pragma clang fp contract(off)
    const float4* L4 = reinterpret_cast<const float4*>(retL);
    const float4* R4 = reinterpret_cast<const float4*>(retR);
    float f = 0.0f, e = 0.0f, r = 0.0f, cp = 0.0f;
#pragma unroll
    for (int it = 0; it < 4; ++it) {
      int g = lane + (it << 6);           // 0..255 over 200 float4s
      if (g < 200) {
        float4 q = (g < 100) ? L4[g] : R4[g - 100];
        CLS(q.x); CLS(q.y); CLS(q.z); CLS(q.w);
      }
    }
#pragma unroll
    for (int off = 1; off < 64; off <<= 1) {
      f  += __shfl_xor(f,  off);
      e  += __shfl_xor(e,  off);
      r  += __shfl_xor(r,  off);
      cp += __shfl_xor(cp, off);
    }
    float total = f + e + r + cp + 1e-8f;
    int pp = (lane >> 3) & 3;
    float dv;
    if (pp == 0)      dv = (f * 0.1f + e * 0.05f + cp * 0.8f + r * 0.2f) / total;
    else if (pp == 1) dv = (f * 0.2f + e * 0.1f  + cp * 0.5f + r * 0.3f) / total;
    else if (pp == 2) dv = (f * 0.8f + e * 0.3f  + cp * 0.3f + r * 0.3f) / total;
    else              dv = (f * 0.4f + e * 0.7f  + cp * 0.2f + r * 0.3f) / total;
    float Ib = dv * 10.0f + (-2.0f);
    Ib140 = Ib + 140.0f;
  }

  // ---- recurrence ----
  float v = -65.0f;
  float U = -3250.0f;   // 250 * u0, u0 = -13 exactly
  float R = 0.0f;       // rate / 0.05

  int t = 0;
  if (main_path) {
    for (; t + 48 <= S; t += 32) {
      LOAD16(n, p); p += 16 * 32;          // steps t+16..t+31
      STEP16(c);                           // steps t..t+15
      LOAD16(c, p); p += 16 * 32;          // steps t+32..t+47
      STEP16(n);                           // steps t+16..t+31
    }
    STEP16(c);                             // steps t..t+15
    t += 16;
  }
  // tail: 1-ahead prefetch scalar loop
  {
    const float* q = noise + neuron;
    float cur = (t < S) ? q[(size_t)t * 32] : 0.0f;
    for (; t < S; ++t) {
      float nxt = (t + 1 < S) ? q[(size_t)(t + 1) * 32] : 0.0f;
      FSTEP(cur);
      cur = nxt;
    }
  }

  // ---- outputs ----
  {
#pragma clang fp contract(off)
    float rate = 0.05f * R;
    float rsum = rate;
    rsum += __shfl_xor(rsum, 1);
    rsum += __shfl_xor(rsum, 2);
    rsum += __shfl_xor(rsum, 4);
    float mean = rsum / 8.0f;            // exact /8
    float m_uv = __shfl(mean, 0);
    float m_bl = __shfl(mean, 8);
    float m_gr = __shfl(mean, 16);
    float m_rd = __shfl(mean, 24);
    if (lane == 0) {
      out[0] = m_uv;
      out[1] = m_bl;
      out[2] = m_gr;
      out[3] = m_rd;
      out[4] = m_rd - m_gr;
      out[5] = (m_uv + m_bl) / 2.0f - (m_gr + m_rd) / 2.0f;
    }
  }
}

extern "C" void kernel_launch(void* const* d_in, const int* in_sizes, int n_in,
                              void* d_out, int out_size, void* d_ws,
                              size_t ws_size, hipStream_t stream) {
  const float* retL  = (const float*)d_in[0];
  const float* retR  = (const float*)d_in[1];
  const float* noise = (const float*)d_in[2];
  float* out = (float*)d_out;
  (void)n_in; (void)out_size; (void)d_ws; (void)ws_size;

  const int S = in_sizes[2] / 32;  // substeps
  hipLaunchKernelGGL(scv_kernel, dim3(1), dim3(64), 0, stream, retL, retR,
                     noise, out, S);
}